// Round 2
// baseline (462.411 us; speedup 1.0000x reference)
//
#include <hip/hip_runtime.h>
#include <hip/hip_bf16.h>

// Problem constants: B=32, S=4096, E=512, D=512, H=512
#define BATCH 32
#define SEQ   4096
#define EDIM  512
#define HDIM  512
#define NCHUNK 64                 // S-chunks of 64 rows per batch
#define NBLK  (BATCH * NCHUNK)    // 2048 fused blocks

typedef unsigned short u16;
typedef unsigned int   u32;

typedef __bf16 bf16x8 __attribute__((ext_vector_type(8)));
typedef float  f32x4  __attribute__((ext_vector_type(4)));

__device__ __forceinline__ u16 bf_rne(float x) {
    u32 u = __float_as_uint(x);
    u32 r = (u + 0x7fffu + ((u >> 16) & 1u)) >> 16;   // round-to-nearest-even
    return (u16)r;
}
__device__ __forceinline__ u32 pack2(u16 lo, u16 hi) {
    return (u32)lo | ((u32)hi << 16);
}
__device__ __forceinline__ float tanh_fast(float x) {
    float e = __builtin_amdgcn_exp2f(x * 2.88539008177793f);
    return 1.0f - 2.0f * __builtin_amdgcn_rcpf(e + 1.0f);
}

// ---------------------------------------------------------------------------
// prep_kernel: (a) dec_bias = dec @ W_dec^T + b_dec + b_enc   [blocks 0..4095]
//              (b) pack W_enc fp32 -> bf16 b-fragment layout  [blocks 4096..4223]
// wpack chunk id = (nsub*16 + kc)*64 + lane;
// lane holds W[nsub*16+(l&15)][kc*32+(l>>4)*8+j], j=0..7
// ---------------------------------------------------------------------------
__global__ void prep_kernel(const float* __restrict__ W_enc, uint4* __restrict__ wpack,
                            const float* __restrict__ dec, const float* __restrict__ Wd,
                            const float* __restrict__ b_enc, const float* __restrict__ b_dec,
                            float* __restrict__ dec_bias) {
    int bid = blockIdx.x;
    int t = threadIdx.x;
    if (bid < 4096) {
        int wave = t >> 6, lane = t & 63;
        int p = bid * 4 + wave;
        int b = p >> 9, h = p & 511;
        const float4* wr = reinterpret_cast<const float4*>(Wd)  + h * 128;
        const float4* dr = reinterpret_cast<const float4*>(dec) + b * 128;
        float4 w0 = wr[lane * 2], w1 = wr[lane * 2 + 1];
        float4 d0 = dr[lane * 2], d1 = dr[lane * 2 + 1];
        float s = w0.x * d0.x + w0.y * d0.y + w0.z * d0.z + w0.w * d0.w
                + w1.x * d1.x + w1.y * d1.y + w1.z * d1.z + w1.w * d1.w;
#pragma unroll
        for (int m = 1; m < 64; m <<= 1) s += __shfl_xor(s, m, 64);
        if (lane == 0) dec_bias[p] = s + b_dec[h] + b_enc[h];
    } else {
        int id   = (bid - 4096) * 256 + t;          // 32768 chunks
        int nsub = id >> 10;
        int rem  = id & 1023;
        int kc   = rem >> 6;
        int lane = rem & 63;
        int row  = nsub * 16 + (lane & 15);
        int col  = kc * 32 + (lane >> 4) * 8;
        const float* src = W_enc + row * EDIM + col;
        uint4 o;
        o.x = pack2(bf_rne(src[0]), bf_rne(src[1]));
        o.y = pack2(bf_rne(src[2]), bf_rne(src[3]));
        o.z = pack2(bf_rne(src[4]), bf_rne(src[5]));
        o.w = pack2(bf_rne(src[6]), bf_rne(src[7]));
        wpack[id] = o;
    }
}

// ---------------------------------------------------------------------------
// fused_kernel v3: per block = (batch b, 64-row S-chunk), 512 threads / 8 waves.
//  ROUND-1 POST-MORTEM: barrier removal was neutral -> bottleneck is latency
//  at register-limited occupancy (acc[4][8]=128 + 120 VGPR ~ 248/512 -> only
//  2 waves/SIMD). v3 halves the per-wave register footprint:
//    8 waves x (64 rows x 64 H-cols) tiles -> acc[4][4] = 64 acc regs,
//    bcur[4] single-buffered (reload-after-last-use; next use ~12 MFMAs away,
//    covered by 4 resident waves), af[4] = 16 VGPRs.
//  __launch_bounds__(512,4): reg cap 128/wave -> 4 waves/SIMD (2 blocks/CU,
//  LDS 68.9KB*2 = 138KB < 160KB). Occupancy 25% -> 50% of hardware max.
//  Phase A: stage full 64x512 X tile (fp32->bf16) in LDS once; barrier-free
//           K-loop of 16 steps x {4 ds_read_b128 | 16 MFMA | 4 bcur reloads}.
//  Phase B: local softmax over 64 scores.
//  Phase C: c_loc[e=tid] = sum_s p_s * X[s][e]  (fp32, L2-hot re-read).
// mfma_f32_16x16x32_bf16: A[m=l&15][k=(l>>4)*8+j]; C/D: m=(l>>4)*4+r, n=l&15.
// LDS A row stride 520 u16 = 260 dwords == 4 (mod 32): ds_write_b128 and
// ds_read_b128 both spread 8 dwords/bank = optimal (verified both maps).
// ---------------------------------------------------------------------------
#define ASTRIDE 520

__global__ __launch_bounds__(512, 4) void fused_kernel(
    const float* __restrict__ X, const uint4* __restrict__ Wp,
    const float* __restrict__ bias, const float* __restrict__ v,
    float* __restrict__ cpart, float* __restrict__ mpart, float* __restrict__ lpart)
{
    __shared__ alignas(16) u16 Abuf[64 * ASTRIDE];   // 66560 B
    __shared__ float sred[8][64];                    // 2 KB
    __shared__ float pbuf[64];

    const int tid  = threadIdx.x;
    const int wave = tid >> 6, lane = tid & 63;
    const int quad = lane >> 4, l15 = lane & 15;
    const int blk  = blockIdx.x;          // 2048
    const int b    = blk >> 6;
    const long row0 = (long)blk * 64;
    const float4* X4 = reinterpret_cast<const float4*>(X + row0 * EDIM);

    // staging map: thread -> row r (0..63), column group c8 (0..7).
    // Each thread stages 8 pieces of 8 consecutive floats: piece = p*8 + c8.
    const int r  = tid >> 3;
    const int c8 = tid & 7;

    // ---- Phase A0: stage full tile; all 16 float4 loads in flight (8 KB/wave
    //      outstanding -> good HBM MLP), then convert+write ----
    float4 st[16];
#pragma unroll
    for (int p = 0; p < 8; p++) {
        int piece = p * 8 + c8;
        st[2 * p]     = X4[r * 128 + piece * 2];
        st[2 * p + 1] = X4[r * 128 + piece * 2 + 1];
    }
#pragma unroll
    for (int p = 0; p < 8; p++) {
        int piece = p * 8 + c8;
        uint4 w;
        w.x = pack2(bf_rne(st[2 * p].x),     bf_rne(st[2 * p].y));
        w.y = pack2(bf_rne(st[2 * p].z),     bf_rne(st[2 * p].w));
        w.z = pack2(bf_rne(st[2 * p + 1].x), bf_rne(st[2 * p + 1].y));
        w.w = pack2(bf_rne(st[2 * p + 1].z), bf_rne(st[2 * p + 1].w));
        *reinterpret_cast<uint4*>(&Abuf[r * ASTRIDE + piece * 8]) = w;
    }

    f32x4 acc[4][4] = {};                 // [msub][nsub]: m=64, n=64 per wave
    uint4 bcur[4];
#pragma unroll
    for (int jj = 0; jj < 4; jj++)
        bcur[jj] = Wp[((wave * 4 + jj) * 16 + 0) * 64 + lane];
    __syncthreads();                      // the ONLY barrier before the epilogue

    // ---- Phase A1: barrier-free K-loop, bcur reloaded right after last use ----
#pragma unroll
    for (int ks = 0; ks < 16; ks++) {
        bf16x8 af[4];
#pragma unroll
        for (int i = 0; i < 4; i++)
            af[i] = *reinterpret_cast<const bf16x8*>(
                &Abuf[(i * 16 + l15) * ASTRIDE + ks * 32 + quad * 8]);
#pragma unroll
        for (int jj = 0; jj < 4; jj++) {
            bf16x8 bfr = __builtin_bit_cast(bf16x8, bcur[jj]);
#pragma unroll
            for (int i = 0; i < 4; i++)
                acc[i][jj] = __builtin_amdgcn_mfma_f32_16x16x32_bf16(
                    af[i], bfr, acc[i][jj], 0, 0, 0);
            if (ks < 15)
                bcur[jj] = Wp[((wave * 4 + jj) * 16 + ks + 1) * 64 + lane];
        }
    }

    // ---- epilogue: scores (this wave owns H-cols wave*64 .. wave*64+63) ----
    float hb[4], hv[4];
#pragma unroll
    for (int jj = 0; jj < 4; jj++) {
        int h = wave * 64 + jj * 16 + l15;
        hb[jj] = bias[b * HDIM + h];
        hv[jj] = v[h];
    }
    float s_acc[16];
#pragma unroll
    for (int x = 0; x < 16; x++) s_acc[x] = 0.f;
#pragma unroll
    for (int i = 0; i < 4; i++)
#pragma unroll
        for (int jj = 0; jj < 4; jj++)
#pragma unroll
            for (int rr = 0; rr < 4; rr++)
                s_acc[i * 4 + rr] += hv[jj] * tanh_fast(acc[i][jj][rr] + hb[jj]);

#pragma unroll
    for (int m = 1; m < 16; m <<= 1)
#pragma unroll
        for (int x = 0; x < 16; x++)
            s_acc[x] += __shfl_xor(s_acc[x], m, 16);

    if (l15 == 0) {
#pragma unroll
        for (int x = 0; x < 16; x++) {
            int i = x >> 2, rr = x & 3;
            sred[wave][i * 16 + quad * 4 + rr] = s_acc[x];
        }
    }
    __syncthreads();

    // ---- phase B: local softmax over 64 scores (first 64 threads) ----
    if (tid < 64) {
        float sc = sred[0][tid] + sred[1][tid] + sred[2][tid] + sred[3][tid]
                 + sred[4][tid] + sred[5][tid] + sred[6][tid] + sred[7][tid];
        float mx = sc;
#pragma unroll
        for (int m = 1; m < 64; m <<= 1) mx = fmaxf(mx, __shfl_xor(mx, m, 64));
        float p = __builtin_amdgcn_exp2f((sc - mx) * 1.44269504088896f);
        float l = p;
#pragma unroll
        for (int m = 1; m < 64; m <<= 1) l += __shfl_xor(l, m, 64);
        pbuf[tid] = p;
        if (tid == 0) { mpart[blk] = mx; lpart[blk] = l; }
    }
    __syncthreads();

    // ---- phase C: weighted sum of X tile (L2-hot re-read, fp32 precision) ----
    // thread tid owns output column e=tid; rows stride 512 floats, lanes
    // contiguous -> fully coalesced 256B/wave per row.
    const float* Xc = X + row0 * EDIM + tid;
    float a0 = 0.f, a1 = 0.f;
#pragma unroll 2
    for (int s = 0; s < 64; s += 8) {
        float x[8];
#pragma unroll
        for (int k = 0; k < 8; k++) x[k] = Xc[(s + k) * EDIM];
#pragma unroll
        for (int k = 0; k < 8; k += 2) {
            a0 = fmaf(pbuf[s + k],     x[k],     a0);
            a1 = fmaf(pbuf[s + k + 1], x[k + 1], a1);
        }
    }
    cpart[(long)blk * EDIM + tid] = a0 + a1;
}

// ---------------------------------------------------------------------------
// combine_k: per batch, merge 64 chunk partials (flash-decoding style).
// out[b][e] = sum_i exp(m_i - M) * c_i[e] / sum_i exp(m_i - M) * l_i
// ---------------------------------------------------------------------------
__global__ __launch_bounds__(256) void combine_k(const float* __restrict__ cpart,
                                                 const float* __restrict__ mpart,
                                                 const float* __restrict__ lpart,
                                                 float* __restrict__ out) {
    __shared__ float wbuf[64];
    __shared__ float linv_s;
    int b = blockIdx.x, t = threadIdx.x;
    if (t < 64) {
        float m = mpart[b * 64 + t];
        float M = m;
#pragma unroll
        for (int k = 1; k < 64; k <<= 1) M = fmaxf(M, __shfl_xor(M, k, 64));
        float w = __builtin_amdgcn_exp2f((m - M) * 1.44269504088896f);
        float lw = lpart[b * 64 + t] * w;
        float L = lw;
#pragma unroll
        for (int k = 1; k < 64; k <<= 1) L += __shfl_xor(L, k, 64);
        wbuf[t] = w;
        if (t == 0) linv_s = 1.0f / L;
    }
    __syncthreads();
    const float2* cp = reinterpret_cast<const float2*>(cpart) + (long)b * 64 * 256 + t;
    float ax = 0.f, ay = 0.f;
#pragma unroll 2
    for (int i = 0; i < 64; i += 8) {
        float2 x[8];
#pragma unroll
        for (int k = 0; k < 8; k++) x[k] = cp[(i + k) * 256];
#pragma unroll
        for (int k = 0; k < 8; k++) {
            float w = wbuf[i + k];
            ax = fmaf(w, x[k].x, ax);
            ay = fmaf(w, x[k].y, ay);
        }
    }
    float inv = linv_s;
    reinterpret_cast<float2*>(out)[b * 256 + t] = make_float2(ax * inv, ay * inv);
}

// ---------------------------------------------------------------------------
extern "C" void kernel_launch(void* const* d_in, const int* in_sizes, int n_in,
                              void* d_out, int out_size, void* d_ws, size_t ws_size,
                              hipStream_t stream) {
    const float* X      = (const float*)d_in[0];
    const float* dec    = (const float*)d_in[1];
    const float* W_enc  = (const float*)d_in[2];
    const float* b_enc  = (const float*)d_in[3];
    const float* W_dec  = (const float*)d_in[4];
    const float* b_dec  = (const float*)d_in[5];
    const float* v      = (const float*)d_in[6];
    float* out = (float*)d_out;

    char* ws = (char*)d_ws;
    uint4* wpack    = (uint4*)ws;                          // 512 KB
    float* dec_bias = (float*)(ws + (512 << 10));          // 64 KB
    float* cpart    = (float*)(ws + (576 << 10));          // 2048*512*4 = 4 MB
    float* mpart    = (float*)(ws + (576 << 10) + (4096 << 10));   // 8 KB
    float* lpart    = (float*)(ws + (576 << 10) + (4104 << 10));   // 8 KB

    prep_kernel  <<<4224, 256, 0, stream>>>(W_enc, wpack, dec, W_dec, b_enc, b_dec,
                                            dec_bias);
    fused_kernel <<<NBLK, 512, 0, stream>>>(X, wpack, dec_bias, v, cpart, mpart, lpart);
    combine_k    <<<BATCH, 256, 0, stream>>>(cpart, mpart, lpart, out);
}

// Round 3
// 439.242 us; speedup vs baseline: 1.0527x; 1.0527x over previous
//
#include <hip/hip_runtime.h>
#include <hip/hip_bf16.h>

// Problem constants: B=32, S=4096, E=512, D=512, H=512
#define BATCH 32
#define SEQ   4096
#define EDIM  512
#define HDIM  512
#define NCHUNK 64                 // S-chunks of 64 rows per batch
#define NBLK  (BATCH * NCHUNK)    // 2048 fused blocks

typedef unsigned short u16;
typedef unsigned int   u32;

typedef __bf16 bf16x8 __attribute__((ext_vector_type(8)));
typedef float  f32x4  __attribute__((ext_vector_type(4)));

__device__ __forceinline__ u16 bf_rne(float x) {
    u32 u = __float_as_uint(x);
    u32 r = (u + 0x7fffu + ((u >> 16) & 1u)) >> 16;   // round-to-nearest-even
    return (u16)r;
}
__device__ __forceinline__ u32 pack2(u16 lo, u16 hi) {
    return (u32)lo | ((u32)hi << 16);
}
__device__ __forceinline__ float tanh_fast(float x) {
    float e = __builtin_amdgcn_exp2f(x * 2.88539008177793f);
    return 1.0f - 2.0f * __builtin_amdgcn_rcpf(e + 1.0f);
}

// ---------------------------------------------------------------------------
// prep_kernel: (a) dec_bias = dec @ W_dec^T + b_dec + b_enc   [blocks 0..4095]
//              (b) pack W_enc fp32 -> bf16 b-fragment layout  [blocks 4096..4223]
// wpack chunk id = (nsub*16 + kc)*64 + lane;
// lane holds W[nsub*16+(l&15)][kc*32+(l>>4)*8+j], j=0..7
// ---------------------------------------------------------------------------
__global__ void prep_kernel(const float* __restrict__ W_enc, uint4* __restrict__ wpack,
                            const float* __restrict__ dec, const float* __restrict__ Wd,
                            const float* __restrict__ b_enc, const float* __restrict__ b_dec,
                            float* __restrict__ dec_bias) {
    int bid = blockIdx.x;
    int t = threadIdx.x;
    if (bid < 4096) {
        int wave = t >> 6, lane = t & 63;
        int p = bid * 4 + wave;
        int b = p >> 9, h = p & 511;
        const float4* wr = reinterpret_cast<const float4*>(Wd)  + h * 128;
        const float4* dr = reinterpret_cast<const float4*>(dec) + b * 128;
        float4 w0 = wr[lane * 2], w1 = wr[lane * 2 + 1];
        float4 d0 = dr[lane * 2], d1 = dr[lane * 2 + 1];
        float s = w0.x * d0.x + w0.y * d0.y + w0.z * d0.z + w0.w * d0.w
                + w1.x * d1.x + w1.y * d1.y + w1.z * d1.z + w1.w * d1.w;
#pragma unroll
        for (int m = 1; m < 64; m <<= 1) s += __shfl_xor(s, m, 64);
        if (lane == 0) dec_bias[p] = s + b_dec[h] + b_enc[h];
    } else {
        int id   = (bid - 4096) * 256 + t;          // 32768 chunks
        int nsub = id >> 10;
        int rem  = id & 1023;
        int kc   = rem >> 6;
        int lane = rem & 63;
        int row  = nsub * 16 + (lane & 15);
        int col  = kc * 32 + (lane >> 4) * 8;
        const float* src = W_enc + row * EDIM + col;
        uint4 o;
        o.x = pack2(bf_rne(src[0]), bf_rne(src[1]));
        o.y = pack2(bf_rne(src[2]), bf_rne(src[3]));
        o.z = pack2(bf_rne(src[4]), bf_rne(src[5]));
        o.w = pack2(bf_rne(src[6]), bf_rne(src[7]));
        wpack[id] = o;
    }
}

// ---------------------------------------------------------------------------
// fused_kernel v4: per block = (batch b, 64-row S-chunk), 512 threads / 8 waves.
//  ROUND-2 POST-MORTEM: v3 spilled ~25 VGPR/thread (WRITE_SIZE 4->107 MB):
//  staging held st[16]=64 VGPRs on top of acc 64 + bcur 16 under the 128-reg
//  cap of __launch_bounds__(512,4). v4 stages in 4 batches of 4 float4
//  (#pragma unroll 1) -> transient 16 regs, peak ~112 < 128, no spill.
//  MLP check: 4 x 16B in flight/thread x 1024 lanes/CU = 32 KB/CU outstanding
//  >> ~9 KB/CU needed for 6.3 TB/s, so staging stays HBM-BW-bound.
//  8 waves x (64 rows x 64 H-cols): acc[4][4]=64 acc regs, bcur[4] reloaded
//  after last use (next use ~12 MFMAs away, covered by 4 waves/SIMD TLP).
//  LDS 67.3KB -> 2 blocks/CU; occupancy target 16 waves/CU (50%).
//  Phase A: stage full 64x512 X tile (fp32->bf16) in LDS once; barrier-free
//           K-loop of 16 steps x {4 ds_read_b128 | 16 MFMA | 4 bcur reloads}.
//  Phase B: local softmax over 64 scores.
//  Phase C: c_loc[e=tid] = sum_s p_s * X[s][e]  (fp32, L2-hot re-read).
// mfma_f32_16x16x32_bf16: A[m=l&15][k=(l>>4)*8+j]; C/D: m=(l>>4)*4+r, n=l&15.
// LDS A row stride 520 u16 = 260 dwords == 4 (mod 32): ds_write_b128 and
// ds_read_b128 both spread 8 dwords/bank = optimal (verified both maps).
// ---------------------------------------------------------------------------
#define ASTRIDE 520

__global__ __launch_bounds__(512, 4) void fused_kernel(
    const float* __restrict__ X, const uint4* __restrict__ Wp,
    const float* __restrict__ bias, const float* __restrict__ v,
    float* __restrict__ cpart, float* __restrict__ mpart, float* __restrict__ lpart)
{
    __shared__ alignas(16) u16 Abuf[64 * ASTRIDE];   // 66560 B
    __shared__ float sred[8][64];                    // 2 KB
    __shared__ float pbuf[64];

    const int tid  = threadIdx.x;
    const int wave = tid >> 6, lane = tid & 63;
    const int quad = lane >> 4, l15 = lane & 15;
    const int blk  = blockIdx.x;          // 2048
    const int b    = blk >> 6;
    const long row0 = (long)blk * 64;
    const float4* X4 = reinterpret_cast<const float4*>(X + row0 * EDIM);

    // staging map: thread -> row r (0..63), column group c8 (0..7).
    // Each thread stages 8 pieces of 8 consecutive floats: piece = p*8 + c8.
    const int r  = tid >> 3;
    const int c8 = tid & 7;
    const float4* Xr = X4 + r * 128;
    u16* Arow = &Abuf[r * ASTRIDE];

    // ---- Phase A0: stage full tile in 4 low-register batches.
    //      unroll 1: keeps transient pressure at 4 float4 = 16 VGPRs (v3's
    //      single 16-float4 batch spiked to 64 and spilled under the 128 cap).
#pragma unroll 1
    for (int g = 0; g < 4; g++) {
        int pieceA = (g * 2) * 8 + c8;
        int pieceB = (g * 2 + 1) * 8 + c8;
        float4 a0 = Xr[pieceA * 2], a1 = Xr[pieceA * 2 + 1];
        float4 b0 = Xr[pieceB * 2], b1 = Xr[pieceB * 2 + 1];
        uint4 wa, wb;
        wa.x = pack2(bf_rne(a0.x), bf_rne(a0.y));
        wa.y = pack2(bf_rne(a0.z), bf_rne(a0.w));
        wa.z = pack2(bf_rne(a1.x), bf_rne(a1.y));
        wa.w = pack2(bf_rne(a1.z), bf_rne(a1.w));
        wb.x = pack2(bf_rne(b0.x), bf_rne(b0.y));
        wb.y = pack2(bf_rne(b0.z), bf_rne(b0.w));
        wb.z = pack2(bf_rne(b1.x), bf_rne(b1.y));
        wb.w = pack2(bf_rne(b1.z), bf_rne(b1.w));
        *reinterpret_cast<uint4*>(&Arow[pieceA * 8]) = wa;
        *reinterpret_cast<uint4*>(&Arow[pieceB * 8]) = wb;
    }

    f32x4 acc[4][4] = {};                 // [msub][nsub]: m=64, n=64 per wave
    uint4 bcur[4];
#pragma unroll
    for (int jj = 0; jj < 4; jj++)
        bcur[jj] = Wp[((wave * 4 + jj) * 16 + 0) * 64 + lane];
    __syncthreads();                      // the ONLY barrier before the epilogue

    // ---- Phase A1: barrier-free K-loop, bcur reloaded right after last use ----
#pragma unroll
    for (int ks = 0; ks < 16; ks++) {
        bf16x8 af[4];
#pragma unroll
        for (int i = 0; i < 4; i++)
            af[i] = *reinterpret_cast<const bf16x8*>(
                &Abuf[(i * 16 + l15) * ASTRIDE + ks * 32 + quad * 8]);
#pragma unroll
        for (int jj = 0; jj < 4; jj++) {
            bf16x8 bfr = __builtin_bit_cast(bf16x8, bcur[jj]);
#pragma unroll
            for (int i = 0; i < 4; i++)
                acc[i][jj] = __builtin_amdgcn_mfma_f32_16x16x32_bf16(
                    af[i], bfr, acc[i][jj], 0, 0, 0);
            if (ks < 15)
                bcur[jj] = Wp[((wave * 4 + jj) * 16 + ks + 1) * 64 + lane];
        }
    }

    // ---- epilogue: scores (this wave owns H-cols wave*64 .. wave*64+63) ----
    float hb[4], hv[4];
#pragma unroll
    for (int jj = 0; jj < 4; jj++) {
        int h = wave * 64 + jj * 16 + l15;
        hb[jj] = bias[b * HDIM + h];
        hv[jj] = v[h];
    }
    float s_acc[16];
#pragma unroll
    for (int x = 0; x < 16; x++) s_acc[x] = 0.f;
#pragma unroll
    for (int i = 0; i < 4; i++)
#pragma unroll
        for (int jj = 0; jj < 4; jj++)
#pragma unroll
            for (int rr = 0; rr < 4; rr++)
                s_acc[i * 4 + rr] += hv[jj] * tanh_fast(acc[i][jj][rr] + hb[jj]);

#pragma unroll
    for (int m = 1; m < 16; m <<= 1)
#pragma unroll
        for (int x = 0; x < 16; x++)
            s_acc[x] += __shfl_xor(s_acc[x], m, 16);

    if (l15 == 0) {
#pragma unroll
        for (int x = 0; x < 16; x++) {
            int i = x >> 2, rr = x & 3;
            sred[wave][i * 16 + quad * 4 + rr] = s_acc[x];
        }
    }
    __syncthreads();

    // ---- phase B: local softmax over 64 scores (first 64 threads) ----
    if (tid < 64) {
        float sc = sred[0][tid] + sred[1][tid] + sred[2][tid] + sred[3][tid]
                 + sred[4][tid] + sred[5][tid] + sred[6][tid] + sred[7][tid];
        float mx = sc;
#pragma unroll
        for (int m = 1; m < 64; m <<= 1) mx = fmaxf(mx, __shfl_xor(mx, m, 64));
        float p = __builtin_amdgcn_exp2f((sc - mx) * 1.44269504088896f);
        float l = p;
#pragma unroll
        for (int m = 1; m < 64; m <<= 1) l += __shfl_xor(l, m, 64);
        pbuf[tid] = p;
        if (tid == 0) { mpart[blk] = mx; lpart[blk] = l; }
    }
    __syncthreads();

    // ---- phase C: weighted sum of X tile (L2-hot re-read, fp32 precision) ----
    // thread tid owns output column e=tid; rows stride 512 floats, lanes
    // contiguous -> fully coalesced 2KB/row across the block.
    const float* Xc = X + row0 * EDIM + tid;
    float a0 = 0.f, a1 = 0.f;
#pragma unroll 2
    for (int s = 0; s < 64; s += 8) {
        float x[8];
#pragma unroll
        for (int k = 0; k < 8; k++) x[k] = Xc[(s + k) * EDIM];
#pragma unroll
        for (int k = 0; k < 8; k += 2) {
            a0 = fmaf(pbuf[s + k],     x[k],     a0);
            a1 = fmaf(pbuf[s + k + 1], x[k + 1], a1);
        }
    }
    cpart[(long)blk * EDIM + tid] = a0 + a1;
}

// ---------------------------------------------------------------------------
// combine_k: per batch, merge 64 chunk partials (flash-decoding style).
// out[b][e] = sum_i exp(m_i - M) * c_i[e] / sum_i exp(m_i - M) * l_i
// ---------------------------------------------------------------------------
__global__ __launch_bounds__(256) void combine_k(const float* __restrict__ cpart,
                                                 const float* __restrict__ mpart,
                                                 const float* __restrict__ lpart,
                                                 float* __restrict__ out) {
    __shared__ float wbuf[64];
    __shared__ float linv_s;
    int b = blockIdx.x, t = threadIdx.x;
    if (t < 64) {
        float m = mpart[b * 64 + t];
        float M = m;
#pragma unroll
        for (int k = 1; k < 64; k <<= 1) M = fmaxf(M, __shfl_xor(M, k, 64));
        float w = __builtin_amdgcn_exp2f((m - M) * 1.44269504088896f);
        float lw = lpart[b * 64 + t] * w;
        float L = lw;
#pragma unroll
        for (int k = 1; k < 64; k <<= 1) L += __shfl_xor(L, k, 64);
        wbuf[t] = w;
        if (t == 0) linv_s = 1.0f / L;
    }
    __syncthreads();
    const float2* cp = reinterpret_cast<const float2*>(cpart) + (long)b * 64 * 256 + t;
    float ax = 0.f, ay = 0.f;
#pragma unroll 2
    for (int i = 0; i < 64; i += 8) {
        float2 x[8];
#pragma unroll
        for (int k = 0; k < 8; k++) x[k] = cp[(i + k) * 256];
#pragma unroll
        for (int k = 0; k < 8; k++) {
            float w = wbuf[i + k];
            ax = fmaf(w, x[k].x, ax);
            ay = fmaf(w, x[k].y, ay);
        }
    }
    float inv = linv_s;
    reinterpret_cast<float2*>(out)[b * 256 + t] = make_float2(ax * inv, ay * inv);
}

// ---------------------------------------------------------------------------
extern "C" void kernel_launch(void* const* d_in, const int* in_sizes, int n_in,
                              void* d_out, int out_size, void* d_ws, size_t ws_size,
                              hipStream_t stream) {
    const float* X      = (const float*)d_in[0];
    const float* dec    = (const float*)d_in[1];
    const float* W_enc  = (const float*)d_in[2];
    const float* b_enc  = (const float*)d_in[3];
    const float* W_dec  = (const float*)d_in[4];
    const float* b_dec  = (const float*)d_in[5];
    const float* v      = (const float*)d_in[6];
    float* out = (float*)d_out;

    char* ws = (char*)d_ws;
    uint4* wpack    = (uint4*)ws;                          // 512 KB
    float* dec_bias = (float*)(ws + (512 << 10));          // 64 KB
    float* cpart    = (float*)(ws + (576 << 10));          // 2048*512*4 = 4 MB
    float* mpart    = (float*)(ws + (576 << 10) + (4096 << 10));   // 8 KB
    float* lpart    = (float*)(ws + (576 << 10) + (4104 << 10));   // 8 KB

    prep_kernel  <<<4224, 256, 0, stream>>>(W_enc, wpack, dec, W_dec, b_enc, b_dec,
                                            dec_bias);
    fused_kernel <<<NBLK, 512, 0, stream>>>(X, wpack, dec_bias, v, cpart, mpart, lpart);
    combine_k    <<<BATCH, 256, 0, stream>>>(cpart, mpart, lpart, out);
}